// Round 13
// baseline (445.928 us; speedup 1.0000x reference)
//
#include <hip/hip_runtime.h>

typedef unsigned short u16;
typedef unsigned int u32;
typedef __attribute__((ext_vector_type(8))) short short8;
typedef __attribute__((ext_vector_type(4))) float floatx4;

#define P_PAIRS 160000
#define N_ATOMS 10000

#define OFF_WMLP  0      // stored TRANSPOSED: [50][64]
#define OFF_BMLP  3200
#define OFF_WE1   3250
#define OFF_BE1   6930
#define OFF_WE2   6962
#define OFF_BE2   7986
#define OFF_WATT  8018
#define OFF_BATT  8242
#define OFF_WN1   8249
#define OFF_BN1   17465
#define OFF_WN2   17497
#define OFF_BN2   18521
#define OFF_WP1   18553
#define OFF_BP1   25721
#define OFF_WP2   25753
#define OFF_BP2   26777
#define OFF_WV1   26809
#define OFF_BV1   27833
#define OFF_WV2   27865
#define OFF_WVMIX 27897
#define WF_TOTAL  28121

__device__ __forceinline__ float b2f(u16 u){ return __uint_as_float(((u32)u) << 16); }
__device__ __forceinline__ u16 f2b(float f){
  u32 u = __float_as_uint(f);
  u32 r = (u + 0x7FFFu + ((u >> 16) & 1u)) >> 16;
  return (u16)r;
}
__device__ __forceinline__ float siluf(float v){ return v / (1.f + __expf(-v)); }
__device__ __forceinline__ float ldw(const void* p, int o, int bf){
  return bf ? b2f(((const u16*)p)[o]) : ((const float*)p)[o];
}

__global__ void k_code(float* out, float code){
  if (threadIdx.x == 0 && blockIdx.x == 0) out[0] = code;
}

// ---------------- dtype detection ----------------
__global__ void k_detect(const u32* __restrict__ hw, const u32* __restrict__ plw,
                         int* __restrict__ flags){
  if (threadIdx.x == 0 && blockIdx.x == 0){
    int bf = 0;
    for (int k = 0; k < 64; ++k){
      u32 e = (hw[k] >> 7) & 0xFFu;
      if (e >= 100u && e <= 140u) bf++;
    }
    flags[0] = (bf >= 48) ? 1 : 0;
    int z = 0;
    for (int k = 0; k < 64; ++k) if (plw[2*k+1] == 0u) z++;
    flags[1] = (z >= 60) ? 1 : 0;
  }
}

// ---------------- input normalization (+ fused idx_i histogram) ------------
__global__ void k_norm(const void* __restrict__ h_raw, const void* __restrict__ x_raw,
                       const void* __restrict__ v_raw, const void* __restrict__ pl_raw,
                       const int* __restrict__ flags, float* __restrict__ hf,
                       float* __restrict__ xf, float* __restrict__ vf, int* __restrict__ pli,
                       int* __restrict__ counts){
  int t = blockIdx.x * 256 + threadIdx.x;
  int bf = flags[0], i64 = flags[1];
  if (t < 320000){
    hf[t] = ldw(h_raw, t, bf);
  } else if (t < 350000){
    int i = t - 320000;
    xf[i] = ldw(x_raw, i, bf);
  } else if (t < 380000){
    int i = t - 350000;
    vf[i] = ldw(v_raw, i, bf);
  } else if (t < 700000){
    int k = t - 380000;
    const int* p32 = (const int*)pl_raw;
    int val = i64 ? p32[2*(size_t)k] : p32[k];
    pli[k] = val;
    if (k < P_PAIRS) atomicAdd(&counts[val], 1);
  }
}

// ---------------- weight conversion -> fp32 (WMLP stored transposed) --------
__global__ void k_convert(const void* w_mlp, const void* b_mlp, const void* w_e1, const void* b_e1,
  const void* w_e2, const void* b_e2, const void* w_att, const void* b_att,
  const void* w_n1, const void* b_n1, const void* w_n2, const void* b_n2,
  const void* w_p1, const void* b_p1, const void* w_p2, const void* b_p2,
  const void* w_v1, const void* b_v1, const void* w_v2, const void* w_vmix,
  const int* __restrict__ flags, float* __restrict__ Wf){
  int t = blockIdx.x * 256 + threadIdx.x;
  if (t >= WF_TOTAL) return;
  int bf = flags[0];
  if (t < 3200){
    int k = t / 50, o = t - k * 50;
    Wf[OFF_WMLP + o * 64 + k] = ldw(w_mlp, t, bf);
    return;
  }
  const void* src; int o;
  if      (t < 3250)  { src = b_mlp;  o = t - 3200; }
  else if (t < 6930)  { src = w_e1;   o = t - 3250; }
  else if (t < 6962)  { src = b_e1;   o = t - 6930; }
  else if (t < 7986)  { src = w_e2;   o = t - 6962; }
  else if (t < 8018)  { src = b_e2;   o = t - 7986; }
  else if (t < 8242)  { src = w_att;  o = t - 8018; }
  else if (t < 8249)  { src = b_att;  o = t - 8242; }
  else if (t < 17465) { src = w_n1;   o = t - 8249; }
  else if (t < 17497) { src = b_n1;   o = t - 17465; }
  else if (t < 18521) { src = w_n2;   o = t - 17497; }
  else if (t < 18553) { src = b_n2;   o = t - 18521; }
  else if (t < 25721) { src = w_p1;   o = t - 18553; }
  else if (t < 25753) { src = b_p1;   o = t - 25721; }
  else if (t < 26777) { src = w_p2;   o = t - 25753; }
  else if (t < 26809) { src = b_p2;   o = t - 26777; }
  else if (t < 27833) { src = w_v1;   o = t - 26809; }
  else if (t < 27865) { src = b_v1;   o = t - 27833; }
  else if (t < 27897) { src = w_v2;   o = t - 27865; }
  else                { src = w_vmix; o = t - 27897; }
  Wf[t] = ldw(src, o, bf);
}

// wT[n][k] = w_xmix[k][n] as bf16
__global__ void k_transpose(const void* __restrict__ wx, const int* __restrict__ flags,
                            u16* __restrict__ wT){
  int t = blockIdx.x * 256 + threadIdx.x;
  if (t >= 224 * 224) return;
  int n = t / 224, k = t - n * 224;
  wT[t] = f2b(ldw(wx, k * 224 + n, flags[0]));
}

// ---------------- counting sort ----------------
__global__ void k_scan(const int* __restrict__ counts, int* __restrict__ offs, int* __restrict__ cursor){
  __shared__ int part[256];
  int t = threadIdx.x;
  int sum = 0;
  for (int k = 0; k < 40; ++k){
    int idx = t * 40 + k;
    if (idx < N_ATOMS) sum += counts[idx];
  }
  part[t] = sum;
  __syncthreads();
  if (t == 0){
    int run = 0;
    for (int q = 0; q < 256; ++q){ int tmp = part[q]; part[q] = run; run += tmp; }
  }
  __syncthreads();
  int run = part[t];
  for (int k = 0; k < 40; ++k){
    int idx = t * 40 + k;
    if (idx < N_ATOMS){ offs[idx] = run; cursor[idx] = run; run += counts[idx]; }
  }
  if (t == 0) offs[N_ATOMS] = P_PAIRS;
}

__global__ void k_scatter(const int* __restrict__ pl, int* __restrict__ cursor,
                          int* __restrict__ perm, int* __restrict__ aid){
  int p = blockIdx.x * 256 + threadIdx.x;
  int i = pl[p];
  int pos = atomicAdd(&cursor[i], 1);
  perm[pos] = p;
  aid[pos] = i;
}

// ------- per-pair edge model (sorted slots; fused filt; split dot) ---------
__global__ __launch_bounds__(256, 1) void k_pair(const float* __restrict__ h, const float* __restrict__ x,
    const int* __restrict__ pl, const int* __restrict__ perm, const float* __restrict__ Wf,
    u16* __restrict__ edge, float* __restrict__ logits, float* __restrict__ dirs){
  int tid = threadIdx.x;
  int s = blockIdx.x * 256 + tid;
  int p = perm[s];
  int i = pl[p], j = pl[P_PAIRS + p];
  float hl[64];
  {
    const float4* a4 = (const float4*)(h + (size_t)i * 32);
    const float4* b4 = (const float4*)(h + (size_t)j * 32);
    #pragma unroll
    for (int q = 0; q < 8; ++q){
      float4 t = a4[q];
      hl[q*4+0] = t.x; hl[q*4+1] = t.y; hl[q*4+2] = t.z; hl[q*4+3] = t.w;
    }
    #pragma unroll
    for (int q = 0; q < 8; ++q){
      float4 t = b4[q];
      hl[32+q*4+0] = t.x; hl[32+q*4+1] = t.y; hl[32+q*4+2] = t.z; hl[32+q*4+3] = t.w;
    }
  }
  float r0 = x[j*3+0] - x[i*3+0];
  float r1 = x[j*3+1] - x[i*3+1];
  float r2 = x[j*3+2] - x[i*3+2];
  float d = sqrtf(r0*r0 + r1*r1 + r2*r2);
  float rinv = 1.f / (d + 1e-5f);
  dirs[s*3+0] = r0*rinv; dirs[s*3+1] = r1*rinv; dirs[s*3+2] = r2*rinv;

  float u[32];
  #pragma unroll
  for (int o = 0; o < 32; ++o) u[o] = Wf[OFF_BE1 + o];
  for (int k = 0; k < 64; ++k){
    float ek = hl[k];
    const float* wr = Wf + OFF_WE1 + k * 32;
    #pragma unroll
    for (int o = 0; o < 32; ++o) u[o] += ek * wr[o];
  }
  {
    const float* wr = Wf + OFF_WE1 + 114 * 32;
    #pragma unroll
    for (int o = 0; o < 32; ++o) u[o] += d * wr[o];
  }
  for (int kk = 0; kk < 50; ++kk){
    const float* wm = Wf + OFF_WMLP + kk * 64;
    float d0 = Wf[OFF_BMLP + kk], d1 = 0.f, d2 = 0.f, d3 = 0.f;
    #pragma unroll
    for (int k = 0; k < 64; k += 4){
      d0 += hl[k]   * wm[k];
      d1 += hl[k+1] * wm[k+1];
      d2 += hl[k+2] * wm[k+2];
      d3 += hl[k+3] * wm[k+3];
    }
    float dot = (d0 + d1) + (d2 + d3);
    float c = (float)kk * (5.0f / 49.0f);
    float dd = d - c;
    float filt = dot * __expf(-10.0f * dd * dd);
    const float* we = Wf + OFF_WE1 + (64 + kk) * 32;
    #pragma unroll
    for (int o = 0; o < 32; ++o) u[o] += filt * we[o];
  }
  #pragma unroll
  for (int o = 0; o < 32; ++o) u[o] = siluf(u[o]);
  float eg[32];
  #pragma unroll
  for (int o = 0; o < 32; ++o) eg[o] = Wf[OFF_BE2 + o];
  #pragma unroll
  for (int k = 0; k < 32; ++k){
    const float* wr = Wf + OFF_WE2 + k * 32;
    #pragma unroll
    for (int o = 0; o < 32; ++o) eg[o] += u[k] * wr[o];
  }
  {
    u32 st[16];
    #pragma unroll
    for (int o = 0; o < 16; ++o)
      st[o] = (u32)f2b(eg[2*o]) | ((u32)f2b(eg[2*o+1]) << 16);
    #pragma unroll
    for (int q = 0; q < 4; ++q){
      uint4 vv; vv.x = st[4*q]; vv.y = st[4*q+1]; vv.z = st[4*q+2]; vv.w = st[4*q+3];
      *(uint4*)(edge + (size_t)s * 32 + q * 8) = vv;
    }
  }
  float lg[7];
  #pragma unroll
  for (int o = 0; o < 7; ++o) lg[o] = Wf[OFF_BATT + o];
  #pragma unroll
  for (int k = 0; k < 32; ++k){
    const float* wr = Wf + OFF_WATT + k * 7;
    #pragma unroll
    for (int o = 0; o < 7; ++o) lg[o] += eg[k] * wr[o];
  }
  #pragma unroll
  for (int o = 0; o < 7; ++o){
    float vv = lg[o];
    float cl = vv > 0.f ? vv : 2.f * expm1f(0.5f * vv);
    logits[s*7+o] = cl;
  }
}

// ---------------- segment softmax: 16-lane group per atom ----------------
__global__ __launch_bounds__(256) void k_att(const int* __restrict__ offs,
    const float* __restrict__ logits, float* __restrict__ atts){
  int a = blockIdx.x * 16 + (threadIdx.x >> 4);
  int lane = threadIdx.x & 15;
  int off = offs[a], end = offs[a+1];
  float m[7];
  #pragma unroll
  for (int hh = 0; hh < 7; ++hh) m[hh] = -1e30f;
  for (int s = off + lane; s < end; s += 16){
    #pragma unroll
    for (int hh = 0; hh < 7; ++hh) m[hh] = fmaxf(m[hh], logits[s*7+hh]);
  }
  #pragma unroll
  for (int hh = 0; hh < 7; ++hh){
    float v = m[hh];
    #pragma unroll
    for (int msk = 8; msk >= 1; msk >>= 1) v = fmaxf(v, __shfl_xor(v, msk));
    m[hh] = v;
  }
  float sm[7] = {0,0,0,0,0,0,0};
  for (int s = off + lane; s < end; s += 16){
    #pragma unroll
    for (int hh = 0; hh < 7; ++hh){
      float e = __expf(logits[s*7+hh] - m[hh]);
      sm[hh] += e;
      atts[s*7+hh] = e;
    }
  }
  #pragma unroll
  for (int hh = 0; hh < 7; ++hh){
    float v = sm[hh];
    #pragma unroll
    for (int msk = 8; msk >= 1; msk >>= 1) v += __shfl_xor(v, msk);
    sm[hh] = 1.f / v;
  }
  for (int s = off + lane; s < end; s += 16){
    #pragma unroll
    for (int hh = 0; hh < 7; ++hh) atts[s*7+hh] *= sm[hh];
  }
}

// ------- MFMA GEMM + in-block segmented comb/hsem reduction ----------------
// LDS: As bf16[128][40] @0 | Bs bf16[224][40] @10240 | eL u16[128][32] @28160
//      aL f32[128][7] @36352 ; phase2 xt bf16[128][232] @0 (59392)
//      persistent: dL f32[128][3] @59392 | iL i32[128] @60928 -> 61440
#define G4_BS   10240
#define G4_EL   28160
#define G4_AL   36352
#define G4_DL   59392
#define G4_ID   60928
#define G4_TOT  61440

__global__ __launch_bounds__(256) void k_gemm4(const u16* __restrict__ edge,
    const float* __restrict__ atts, const u16* __restrict__ BT,
    const float* __restrict__ dirs, const int* __restrict__ aid,
    float* __restrict__ comb, float* __restrict__ hsemg){
  __shared__ __attribute__((aligned(16))) char smem[G4_TOT];
  u16*   As = (u16*)smem;
  u16*   Bs = (u16*)(smem + G4_BS);
  u16*   eL = (u16*)(smem + G4_EL);
  float* aL = (float*)(smem + G4_AL);
  float* dL = (float*)(smem + G4_DL);
  int*   iL = (int*)(smem + G4_ID);
  int tid = threadIdx.x;
  int wave = tid >> 6, lane = tid & 63, l15 = lane & 15, quad = lane >> 4;
  int row0 = blockIdx.x * 128;

  if (tid < 128){
    iL[tid] = aid[row0 + tid];
    dL[tid*3+0] = dirs[(row0+tid)*3+0];
    dL[tid*3+1] = dirs[(row0+tid)*3+1];
    dL[tid*3+2] = dirs[(row0+tid)*3+2];
  }
  for (int e = tid; e < 896; e += 256) aL[e] = atts[(size_t)row0*7 + e];
  for (int e = tid; e < 512; e += 256){
    int r = e >> 2, q = e & 3;
    *(uint4*)(eL + r*32 + q*8) = *(const uint4*)(edge + (size_t)(row0 + r)*32 + q*8);
  }
  floatx4 acc[2][14];
  #pragma unroll
  for (int mt = 0; mt < 2; ++mt)
    #pragma unroll
    for (int nt = 0; nt < 14; ++nt)
      acc[mt][nt] = (floatx4){0.f, 0.f, 0.f, 0.f};
  __syncthreads();

  for (int kt = 0; kt < 7; ++kt){
    int kk = kt * 32;
    for (int e = tid; e < 896; e += 256){
      int r = e >> 2, q = e & 3;
      *(uint4*)(Bs + r*40 + q*8) = *(const uint4*)(BT + (size_t)r*224 + kk + q*8);
    }
    for (int e = tid; e < 2048; e += 256){
      int r = e >> 4, c2 = (e & 15) * 2;
      int kc = kk + c2;
      int f0 = kc / 7,  h0 = kc - f0 * 7;
      int kc1 = kc + 1;
      int f1 = kc1 / 7, h1 = kc1 - f1 * 7;
      float v0 = b2f(eL[r*32 + f0]) * aL[r*7 + h0];
      float v1 = b2f(eL[r*32 + f1]) * aL[r*7 + h1];
      ((u32*)As)[r*20 + (e & 15)] = (u32)f2b(v0) | ((u32)f2b(v1) << 16);
    }
    __syncthreads();
    short8 a0 = *(const short8*)(As + (wave*32 + l15)*40 + quad*8);
    short8 a1 = *(const short8*)(As + (wave*32 + 16 + l15)*40 + quad*8);
    #pragma unroll
    for (int nt = 0; nt < 14; ++nt){
      short8 b = *(const short8*)(Bs + (nt*16 + l15)*40 + quad*8);
      acc[0][nt] = __builtin_amdgcn_mfma_f32_16x16x32_bf16(a0, b, acc[0][nt], 0, 0, 0);
      acc[1][nt] = __builtin_amdgcn_mfma_f32_16x16x32_bf16(a1, b, acc[1][nt], 0, 0, 0);
    }
    __syncthreads();
  }
  // tanh -> xt (aliases As/Bs/eL/aL; dL/iL live above)
  u16* xt = (u16*)smem;
  #pragma unroll
  for (int mt = 0; mt < 2; ++mt)
    #pragma unroll
    for (int nt = 0; nt < 14; ++nt)
      #pragma unroll
      for (int reg = 0; reg < 4; ++reg){
        int r = wave*32 + mt*16 + quad*4 + reg;
        int c = nt*16 + l15;
        float vv = acc[mt][nt][reg];
        vv = fminf(fmaxf(vv, -15.f), 15.f);
        float e2 = __expf(2.f * vv);
        xt[r*232 + c] = f2b((e2 - 1.f) / (e2 + 1.f));
      }
  __syncthreads();
  // segmented reduction: comb (dir x tanh) + hsem (edge*att), sorted segments
  // first/last segment of block -> atomicAdd (atom may span 2 blocks); middle -> store
  if (tid < 224){
    int c = tid;
    int f = c / 7, hh = c - f * 7;
    int acur = iL[0];
    int rstart = 0;
    float s0 = 0.f, s1 = 0.f, s2 = 0.f, sh = 0.f;
    for (int r = 0; r < 128; ++r){
      int ar = iL[r];
      if (ar != acur){
        size_t b = ((size_t)acur*224 + c)*3;
        if (rstart == 0){
          atomicAdd(&comb[b+0], s0); atomicAdd(&comb[b+1], s1); atomicAdd(&comb[b+2], s2);
          atomicAdd(&hsemg[(size_t)acur*224 + c], sh);
        } else {
          comb[b+0] = s0; comb[b+1] = s1; comb[b+2] = s2;
          hsemg[(size_t)acur*224 + c] = sh;
        }
        s0 = s1 = s2 = sh = 0.f; acur = ar; rstart = r;
      }
      float xv = b2f(xt[r*232 + c]);
      s0 += dL[r*3+0] * xv;
      s1 += dL[r*3+1] * xv;
      s2 += dL[r*3+2] * xv;
      sh += b2f(edge[(size_t)(row0 + r)*32 + f]) * atts[(size_t)(row0 + r)*7 + hh];
    }
    size_t b = ((size_t)acur*224 + c)*3;
    atomicAdd(&comb[b+0], s0); atomicAdd(&comb[b+1], s1); atomicAdd(&comb[b+2], s2);
    atomicAdd(&hsemg[(size_t)acur*224 + c], sh);
  }
}

// ---------------- final: wave per atom, no slot loop ----------------
__global__ __launch_bounds__(256) void k_final6(const float* __restrict__ h, const float* __restrict__ x,
    const float* __restrict__ v, const float* __restrict__ Wf, const int* __restrict__ offs,
    const float* __restrict__ comb, const float* __restrict__ hsemg, float* __restrict__ out){
  __shared__ float s_nsq[4][224];
  __shared__ float s_hsem[4][224];
  __shared__ float s_u1[4][32], s_sp[4][32], s_g[4][32], s_un[4][32];
  int wv_ = threadIdx.x >> 6, lane = threadIdx.x & 63;
  int a = blockIdx.x * 4 + wv_;                 // N = 2500*4
  int cnt = offs[a+1] - offs[a];
  float inv = 1.f / fmaxf((float)cnt, 1.f);
  float pv0 = 0.f, pv1 = 0.f, pv2 = 0.f;
  if (lane < 56){
    int cbase = lane * 4;
    const float* cb = comb + ((size_t)a*224 + cbase)*3;
    float4 q0 = *(const float4*)(cb);
    float4 q1 = *(const float4*)(cb + 4);
    float4 q2 = *(const float4*)(cb + 8);
    float4 hq = *(const float4*)(hsemg + (size_t)a*224 + cbase);
    float cc[12] = {q0.x,q0.y,q0.z,q0.w, q1.x,q1.y,q1.z,q1.w, q2.x,q2.y,q2.z,q2.w};
    float hv[4] = {hq.x,hq.y,hq.z,hq.w};
    #pragma unroll
    for (int j = 0; j < 4; ++j){
      int c = cbase + j;
      float cm0 = cc[3*j+0]*inv, cm1 = cc[3*j+1]*inv, cm2 = cc[3*j+2]*inv;
      s_nsq[wv_][c] = cm0*cm0 + cm1*cm1 + cm2*cm2;
      s_hsem[wv_][c] = hv[j];
      float wvx = Wf[OFF_WVMIX + c];
      pv0 += wvx*cm0; pv1 += wvx*cm1; pv2 += wvx*cm2;
    }
  }
  #pragma unroll
  for (int m = 32; m >= 1; m >>= 1){
    pv0 += __shfl_xor(pv0, m); pv1 += __shfl_xor(pv1, m); pv2 += __shfl_xor(pv2, m);
  }
  __syncthreads();
  if (lane < 32){
    float u = Wf[OFF_BP1 + lane];
    for (int c = 0; c < 224; ++c) u += s_nsq[wv_][c] * Wf[OFF_WP1 + c*32 + lane];
    s_u1[wv_][lane] = siluf(u);
    float g = Wf[OFF_BV1 + lane];
    #pragma unroll
    for (int k = 0; k < 32; ++k) g += h[a*32+k] * Wf[OFF_WV1 + k*32 + lane];
    s_g[wv_][lane] = siluf(g);
  }
  __syncthreads();
  float zpart = (lane < 32) ? s_g[wv_][lane] * Wf[OFF_WV2 + lane] : 0.f;
  #pragma unroll
  for (int m = 32; m >= 1; m >>= 1) zpart += __shfl_xor(zpart, m);
  float sc = 2.f / (1.f + __expf(-zpart));
  if (lane < 32){
    float u = Wf[OFF_BP2 + lane];
    #pragma unroll
    for (int k = 0; k < 32; ++k) u += s_u1[wv_][k] * Wf[OFF_WP2 + k*32 + lane];
    s_sp[wv_][lane] = siluf(u);
  }
  __syncthreads();
  if (lane < 32){
    float u = Wf[OFF_BN1 + lane];
    #pragma unroll
    for (int k = 0; k < 32; ++k) u += h[a*32+k] * Wf[OFF_WN1 + k*32 + lane];
    for (int c = 0; c < 224; ++c) u += s_hsem[wv_][c] * Wf[OFF_WN1 + (32 + c)*32 + lane];
    #pragma unroll
    for (int k = 0; k < 32; ++k) u += s_sp[wv_][k] * Wf[OFF_WN1 + (256 + k)*32 + lane];
    s_un[wv_][lane] = siluf(u);
  }
  __syncthreads();
  if (lane < 32){
    float u = Wf[OFF_BN2 + lane];
    #pragma unroll
    for (int k = 0; k < 32; ++k) u += s_un[wv_][k] * Wf[OFF_WN2 + k*32 + lane];
    out[a*32+lane] = h[a*32+lane] + siluf(u);
  }
  if (lane < 3){
    float vup = sc * v[a*3+lane] + ((lane == 0) ? pv0 : (lane == 1) ? pv1 : pv2);
    float xup = x[a*3+lane] + vup;
    out[N_ATOMS*32 + a*3 + lane] = xup;
    out[N_ATOMS*32 + N_ATOMS*3 + a*3 + lane] = vup;
  }
}

// ---------------- workspace layout (~62 MB; >=93 MB proven available) -------
static constexpr size_t al256(size_t x){ return (x + 255) & ~(size_t)255; }
static constexpr size_t WS_FLAGS   = 0;
static constexpr size_t WS_COUNTS  = al256(WS_FLAGS + 8);
static constexpr size_t WS_OFFSETS = al256(WS_COUNTS + (size_t)N_ATOMS * 4);
static constexpr size_t WS_CURSOR  = al256(WS_OFFSETS + (size_t)(N_ATOMS + 1) * 4);
static constexpr size_t WS_PERM    = al256(WS_CURSOR + (size_t)N_ATOMS * 4);
static constexpr size_t WS_AID     = al256(WS_PERM + (size_t)P_PAIRS * 4);
static constexpr size_t WS_PLI     = al256(WS_AID + (size_t)P_PAIRS * 4);
static constexpr size_t WS_HF      = al256(WS_PLI + (size_t)2 * P_PAIRS * 4);
static constexpr size_t WS_XF      = al256(WS_HF + (size_t)N_ATOMS * 32 * 4);
static constexpr size_t WS_VF      = al256(WS_XF + (size_t)N_ATOMS * 3 * 4);
static constexpr size_t WS_WF      = al256(WS_VF + (size_t)N_ATOMS * 3 * 4);
static constexpr size_t WS_WT      = al256(WS_WF + (size_t)WF_TOTAL * 4);
static constexpr size_t WS_EDGE    = al256(WS_WT + (size_t)224 * 224 * 2);
static constexpr size_t WS_ATTS    = al256(WS_EDGE + (size_t)P_PAIRS * 32 * 2);
static constexpr size_t WS_DIRS    = al256(WS_ATTS + (size_t)P_PAIRS * 7 * 4);
static constexpr size_t WS_LOGITS  = al256(WS_DIRS + (size_t)P_PAIRS * 3 * 4);
static constexpr size_t WS_COMB    = al256(WS_LOGITS + (size_t)P_PAIRS * 7 * 4);
static constexpr size_t WS_HSEMG   = al256(WS_COMB + (size_t)N_ATOMS * 224 * 3 * 4);
static constexpr size_t WS_END     = WS_HSEMG + (size_t)N_ATOMS * 224 * 4;

extern "C" void kernel_launch(void* const* d_in, const int* in_sizes, int n_in,
                              void* d_out, int out_size, void* d_ws, size_t ws_size,
                              hipStream_t stream){
  (void)in_sizes; (void)n_in;
  if (out_size != 380000 || ws_size < WS_END){
    k_code<<<1, 64, 0, stream>>>((float*)d_out, 14000.f);
    return;
  }
  char* ws = (char*)d_ws;
  int*   flags  = (int*)(ws + WS_FLAGS);
  int*   counts = (int*)(ws + WS_COUNTS);
  int*   offs   = (int*)(ws + WS_OFFSETS);
  int*   cursor = (int*)(ws + WS_CURSOR);
  int*   perm   = (int*)(ws + WS_PERM);
  int*   aid    = (int*)(ws + WS_AID);
  int*   pli    = (int*)(ws + WS_PLI);
  float* hf     = (float*)(ws + WS_HF);
  float* xf     = (float*)(ws + WS_XF);
  float* vf     = (float*)(ws + WS_VF);
  float* Wf     = (float*)(ws + WS_WF);
  u16*   wT     = (u16*)(ws + WS_WT);
  u16*   edge   = (u16*)(ws + WS_EDGE);
  float* atts   = (float*)(ws + WS_ATTS);
  float* dirs   = (float*)(ws + WS_DIRS);
  float* logits = (float*)(ws + WS_LOGITS);
  float* comb   = (float*)(ws + WS_COMB);
  float* hsemg  = (float*)(ws + WS_HSEMG);

  hipMemsetAsync(counts, 0, (size_t)N_ATOMS * 4, stream);
  hipMemsetAsync(comb, 0, (size_t)N_ATOMS * 224 * 3 * 4, stream);
  hipMemsetAsync(hsemg, 0, (size_t)N_ATOMS * 224 * 4, stream);
  k_detect<<<1, 64, 0, stream>>>((const u32*)d_in[0], (const u32*)d_in[3], flags);
  k_norm<<<(700000 + 255) / 256, 256, 0, stream>>>(d_in[0], d_in[1], d_in[2], d_in[3],
                                                   flags, hf, xf, vf, pli, counts);
  k_convert<<<(WF_TOTAL + 255) / 256, 256, 0, stream>>>(
      d_in[4],  d_in[5],  d_in[6],  d_in[7],  d_in[8],  d_in[9],  d_in[10], d_in[11],
      d_in[12], d_in[13], d_in[14], d_in[15], d_in[16], d_in[17], d_in[18], d_in[19],
      d_in[20], d_in[21], d_in[22], d_in[24], flags, Wf);
  k_transpose<<<(224 * 224 + 255) / 256, 256, 0, stream>>>(d_in[23], flags, wT);
  k_scan<<<1, 256, 0, stream>>>(counts, offs, cursor);
  k_scatter<<<P_PAIRS / 256, 256, 0, stream>>>(pli, cursor, perm, aid);
  k_pair<<<P_PAIRS / 256, 256, 0, stream>>>(hf, xf, pli, perm, Wf, edge, logits, dirs);
  k_att<<<N_ATOMS / 16, 256, 0, stream>>>(offs, logits, atts);
  k_gemm4<<<P_PAIRS / 128, 256, 0, stream>>>(edge, atts, wT, dirs, aid, comb, hsemg);
  k_final6<<<N_ATOMS / 4, 256, 0, stream>>>(hf, xf, vf, Wf, offs, comb, hsemg, (float*)d_out);
}

// Round 14
// 428.755 us; speedup vs baseline: 1.0401x; 1.0401x over previous
//
#include <hip/hip_runtime.h>

typedef unsigned short u16;
typedef unsigned int u32;
typedef __attribute__((ext_vector_type(8))) short short8;
typedef __attribute__((ext_vector_type(4))) float floatx4;

#define P_PAIRS 160000
#define N_ATOMS 10000

#define OFF_WMLP  0      // stored TRANSPOSED: [50][64]
#define OFF_BMLP  3200
#define OFF_WE1   3250
#define OFF_BE1   6930
#define OFF_WE2   6962
#define OFF_BE2   7986
#define OFF_WATT  8018
#define OFF_BATT  8242
#define OFF_WN1   8249
#define OFF_BN1   17465
#define OFF_WN2   17497
#define OFF_BN2   18521
#define OFF_WP1   18553
#define OFF_BP1   25721
#define OFF_WP2   25753
#define OFF_BP2   26777
#define OFF_WV1   26809
#define OFF_BV1   27833
#define OFF_WV2   27865
#define OFF_WVMIX 27897
#define WF_TOTAL  28121

__device__ __forceinline__ float b2f(u16 u){ return __uint_as_float(((u32)u) << 16); }
__device__ __forceinline__ u16 f2b(float f){
  u32 u = __float_as_uint(f);
  u32 r = (u + 0x7FFFu + ((u >> 16) & 1u)) >> 16;
  return (u16)r;
}
__device__ __forceinline__ float siluf(float v){ return v / (1.f + __expf(-v)); }
__device__ __forceinline__ float ldw(const void* p, int o, int bf){
  return bf ? b2f(((const u16*)p)[o]) : ((const float*)p)[o];
}

__global__ void k_code(float* out, float code){
  if (threadIdx.x == 0 && blockIdx.x == 0) out[0] = code;
}

// ---------------- dtype detection ----------------
__global__ void k_detect(const u32* __restrict__ hw, const u32* __restrict__ plw,
                         int* __restrict__ flags){
  if (threadIdx.x == 0 && blockIdx.x == 0){
    int bf = 0;
    for (int k = 0; k < 64; ++k){
      u32 e = (hw[k] >> 7) & 0xFFu;
      if (e >= 100u && e <= 140u) bf++;
    }
    flags[0] = (bf >= 48) ? 1 : 0;
    int z = 0;
    for (int k = 0; k < 64; ++k) if (plw[2*k+1] == 0u) z++;
    flags[1] = (z >= 60) ? 1 : 0;
  }
}

// ---------------- input normalization (+ fused idx_i histogram) ------------
__global__ void k_norm(const void* __restrict__ h_raw, const void* __restrict__ x_raw,
                       const void* __restrict__ v_raw, const void* __restrict__ pl_raw,
                       const int* __restrict__ flags, float* __restrict__ hf,
                       float* __restrict__ xf, float* __restrict__ vf, int* __restrict__ pli,
                       int* __restrict__ counts){
  int t = blockIdx.x * 256 + threadIdx.x;
  int bf = flags[0], i64 = flags[1];
  if (t < 320000){
    hf[t] = ldw(h_raw, t, bf);
  } else if (t < 350000){
    int i = t - 320000;
    xf[i] = ldw(x_raw, i, bf);
  } else if (t < 380000){
    int i = t - 350000;
    vf[i] = ldw(v_raw, i, bf);
  } else if (t < 700000){
    int k = t - 380000;
    const int* p32 = (const int*)pl_raw;
    int val = i64 ? p32[2*(size_t)k] : p32[k];
    pli[k] = val;
    if (k < P_PAIRS) atomicAdd(&counts[val], 1);
  }
}

// ---------------- weight conversion -> fp32 (WMLP stored transposed) --------
__global__ void k_convert(const void* w_mlp, const void* b_mlp, const void* w_e1, const void* b_e1,
  const void* w_e2, const void* b_e2, const void* w_att, const void* b_att,
  const void* w_n1, const void* b_n1, const void* w_n2, const void* b_n2,
  const void* w_p1, const void* b_p1, const void* w_p2, const void* b_p2,
  const void* w_v1, const void* b_v1, const void* w_v2, const void* w_vmix,
  const int* __restrict__ flags, float* __restrict__ Wf){
  int t = blockIdx.x * 256 + threadIdx.x;
  if (t >= WF_TOTAL) return;
  int bf = flags[0];
  if (t < 3200){
    int k = t / 50, o = t - k * 50;
    Wf[OFF_WMLP + o * 64 + k] = ldw(w_mlp, t, bf);
    return;
  }
  const void* src; int o;
  if      (t < 3250)  { src = b_mlp;  o = t - 3200; }
  else if (t < 6930)  { src = w_e1;   o = t - 3250; }
  else if (t < 6962)  { src = b_e1;   o = t - 6930; }
  else if (t < 7986)  { src = w_e2;   o = t - 6962; }
  else if (t < 8018)  { src = b_e2;   o = t - 7986; }
  else if (t < 8242)  { src = w_att;  o = t - 8018; }
  else if (t < 8249)  { src = b_att;  o = t - 8242; }
  else if (t < 17465) { src = w_n1;   o = t - 8249; }
  else if (t < 17497) { src = b_n1;   o = t - 17465; }
  else if (t < 18521) { src = w_n2;   o = t - 17497; }
  else if (t < 18553) { src = b_n2;   o = t - 18521; }
  else if (t < 25721) { src = w_p1;   o = t - 18553; }
  else if (t < 25753) { src = b_p1;   o = t - 25721; }
  else if (t < 26777) { src = w_p2;   o = t - 25753; }
  else if (t < 26809) { src = b_p2;   o = t - 26777; }
  else if (t < 27833) { src = w_v1;   o = t - 26809; }
  else if (t < 27865) { src = b_v1;   o = t - 27833; }
  else if (t < 27897) { src = w_v2;   o = t - 27865; }
  else                { src = w_vmix; o = t - 27897; }
  Wf[t] = ldw(src, o, bf);
}

// wT[n][k] = w_xmix[k][n] as bf16
__global__ void k_transpose(const void* __restrict__ wx, const int* __restrict__ flags,
                            u16* __restrict__ wT){
  int t = blockIdx.x * 256 + threadIdx.x;
  if (t >= 224 * 224) return;
  int n = t / 224, k = t - n * 224;
  wT[t] = f2b(ldw(wx, k * 224 + n, flags[0]));
}

// ---------------- counting sort ----------------
__global__ void k_scan(const int* __restrict__ counts, int* __restrict__ offs, int* __restrict__ cursor){
  __shared__ int part[256];
  int t = threadIdx.x;
  int sum = 0;
  for (int k = 0; k < 40; ++k){
    int idx = t * 40 + k;
    if (idx < N_ATOMS) sum += counts[idx];
  }
  part[t] = sum;
  __syncthreads();
  if (t == 0){
    int run = 0;
    for (int q = 0; q < 256; ++q){ int tmp = part[q]; part[q] = run; run += tmp; }
  }
  __syncthreads();
  int run = part[t];
  for (int k = 0; k < 40; ++k){
    int idx = t * 40 + k;
    if (idx < N_ATOMS){ offs[idx] = run; cursor[idx] = run; run += counts[idx]; }
  }
  if (t == 0) offs[N_ATOMS] = P_PAIRS;
}

__global__ void k_scatter(const int* __restrict__ pl, int* __restrict__ cursor,
                          int* __restrict__ perm, int* __restrict__ aid){
  int p = blockIdx.x * 256 + threadIdx.x;
  int i = pl[p];
  int pos = atomicAdd(&cursor[i], 1);
  perm[pos] = p;
  aid[pos] = i;
}

// ------- per-pair edge model (sorted slots; fused filt; split dot) ---------
__global__ __launch_bounds__(256, 1) void k_pair(const float* __restrict__ h, const float* __restrict__ x,
    const int* __restrict__ pl, const int* __restrict__ perm, const float* __restrict__ Wf,
    u16* __restrict__ edge, float* __restrict__ logits, float* __restrict__ dirs){
  int tid = threadIdx.x;
  int s = blockIdx.x * 256 + tid;
  int p = perm[s];
  int i = pl[p], j = pl[P_PAIRS + p];
  float hl[64];
  {
    const float4* a4 = (const float4*)(h + (size_t)i * 32);
    const float4* b4 = (const float4*)(h + (size_t)j * 32);
    #pragma unroll
    for (int q = 0; q < 8; ++q){
      float4 t = a4[q];
      hl[q*4+0] = t.x; hl[q*4+1] = t.y; hl[q*4+2] = t.z; hl[q*4+3] = t.w;
    }
    #pragma unroll
    for (int q = 0; q < 8; ++q){
      float4 t = b4[q];
      hl[32+q*4+0] = t.x; hl[32+q*4+1] = t.y; hl[32+q*4+2] = t.z; hl[32+q*4+3] = t.w;
    }
  }
  float r0 = x[j*3+0] - x[i*3+0];
  float r1 = x[j*3+1] - x[i*3+1];
  float r2 = x[j*3+2] - x[i*3+2];
  float d = sqrtf(r0*r0 + r1*r1 + r2*r2);
  float rinv = 1.f / (d + 1e-5f);
  dirs[s*3+0] = r0*rinv; dirs[s*3+1] = r1*rinv; dirs[s*3+2] = r2*rinv;

  float u[32];
  #pragma unroll
  for (int o = 0; o < 32; ++o) u[o] = Wf[OFF_BE1 + o];
  for (int k = 0; k < 64; ++k){
    float ek = hl[k];
    const float* wr = Wf + OFF_WE1 + k * 32;
    #pragma unroll
    for (int o = 0; o < 32; ++o) u[o] += ek * wr[o];
  }
  {
    const float* wr = Wf + OFF_WE1 + 114 * 32;
    #pragma unroll
    for (int o = 0; o < 32; ++o) u[o] += d * wr[o];
  }
  for (int kk = 0; kk < 50; ++kk){
    const float* wm = Wf + OFF_WMLP + kk * 64;
    float d0 = Wf[OFF_BMLP + kk], d1 = 0.f, d2 = 0.f, d3 = 0.f;
    #pragma unroll
    for (int k = 0; k < 64; k += 4){
      d0 += hl[k]   * wm[k];
      d1 += hl[k+1] * wm[k+1];
      d2 += hl[k+2] * wm[k+2];
      d3 += hl[k+3] * wm[k+3];
    }
    float dot = (d0 + d1) + (d2 + d3);
    float c = (float)kk * (5.0f / 49.0f);
    float dd = d - c;
    float filt = dot * __expf(-10.0f * dd * dd);
    const float* we = Wf + OFF_WE1 + (64 + kk) * 32;
    #pragma unroll
    for (int o = 0; o < 32; ++o) u[o] += filt * we[o];
  }
  #pragma unroll
  for (int o = 0; o < 32; ++o) u[o] = siluf(u[o]);
  float eg[32];
  #pragma unroll
  for (int o = 0; o < 32; ++o) eg[o] = Wf[OFF_BE2 + o];
  #pragma unroll
  for (int k = 0; k < 32; ++k){
    const float* wr = Wf + OFF_WE2 + k * 32;
    #pragma unroll
    for (int o = 0; o < 32; ++o) eg[o] += u[k] * wr[o];
  }
  {
    u32 st[16];
    #pragma unroll
    for (int o = 0; o < 16; ++o)
      st[o] = (u32)f2b(eg[2*o]) | ((u32)f2b(eg[2*o+1]) << 16);
    #pragma unroll
    for (int q = 0; q < 4; ++q){
      uint4 vv; vv.x = st[4*q]; vv.y = st[4*q+1]; vv.z = st[4*q+2]; vv.w = st[4*q+3];
      *(uint4*)(edge + (size_t)s * 32 + q * 8) = vv;
    }
  }
  float lg[7];
  #pragma unroll
  for (int o = 0; o < 7; ++o) lg[o] = Wf[OFF_BATT + o];
  #pragma unroll
  for (int k = 0; k < 32; ++k){
    const float* wr = Wf + OFF_WATT + k * 7;
    #pragma unroll
    for (int o = 0; o < 7; ++o) lg[o] += eg[k] * wr[o];
  }
  #pragma unroll
  for (int o = 0; o < 7; ++o){
    float vv = lg[o];
    float cl = vv > 0.f ? vv : 2.f * expm1f(0.5f * vv);
    logits[s*7+o] = cl;
  }
}

// ---------------- segment softmax: 16-lane group per atom ----------------
__global__ __launch_bounds__(256) void k_att(const int* __restrict__ offs,
    const float* __restrict__ logits, float* __restrict__ atts){
  int a = blockIdx.x * 16 + (threadIdx.x >> 4);
  int lane = threadIdx.x & 15;
  int off = offs[a], end = offs[a+1];
  float m[7];
  #pragma unroll
  for (int hh = 0; hh < 7; ++hh) m[hh] = -1e30f;
  for (int s = off + lane; s < end; s += 16){
    #pragma unroll
    for (int hh = 0; hh < 7; ++hh) m[hh] = fmaxf(m[hh], logits[s*7+hh]);
  }
  #pragma unroll
  for (int hh = 0; hh < 7; ++hh){
    float v = m[hh];
    #pragma unroll
    for (int msk = 8; msk >= 1; msk >>= 1) v = fmaxf(v, __shfl_xor(v, msk));
    m[hh] = v;
  }
  float sm[7] = {0,0,0,0,0,0,0};
  for (int s = off + lane; s < end; s += 16){
    #pragma unroll
    for (int hh = 0; hh < 7; ++hh){
      float e = __expf(logits[s*7+hh] - m[hh]);
      sm[hh] += e;
      atts[s*7+hh] = e;
    }
  }
  #pragma unroll
  for (int hh = 0; hh < 7; ++hh){
    float v = sm[hh];
    #pragma unroll
    for (int msk = 8; msk >= 1; msk >>= 1) v += __shfl_xor(v, msk);
    sm[hh] = 1.f / v;
  }
  for (int s = off + lane; s < end; s += 16){
    #pragma unroll
    for (int hh = 0; hh < 7; ++hh) atts[s*7+hh] *= sm[hh];
  }
}

// ------- MFMA GEMM (barrier-free K-loop) + LDS-only segmented epilogue ------
// LDS: xt bf16[128][232] @0 (59392) | eL u16[128][32] @59392 (8192)
//      aL f32[128][7] @67584 (3584) | dL f32[128][3] @71168 (1536)
//      iL i32[128] @72704 (512)  -> total 73216
#define G5_EL   59392
#define G5_AL   67584
#define G5_DL   71168
#define G5_ID   72704
#define G5_TOT  73216

__global__ __launch_bounds__(256) void k_gemm5(const u16* __restrict__ edge,
    const float* __restrict__ atts, const u16* __restrict__ BT,
    const float* __restrict__ dirs, const int* __restrict__ aid,
    float* __restrict__ comb, float* __restrict__ hsemg){
  __shared__ __attribute__((aligned(16))) char smem[G5_TOT];
  u16*   xt = (u16*)smem;
  u16*   eL = (u16*)(smem + G5_EL);
  float* aL = (float*)(smem + G5_AL);
  float* dL = (float*)(smem + G5_DL);
  int*   iL = (int*)(smem + G5_ID);
  int tid = threadIdx.x;
  int wave = tid >> 6, lane = tid & 63, l15 = lane & 15, quad = lane >> 4;
  int row0 = blockIdx.x * 128;

  if (tid < 128){
    iL[tid] = aid[row0 + tid];
    dL[tid*3+0] = dirs[(row0+tid)*3+0];
    dL[tid*3+1] = dirs[(row0+tid)*3+1];
    dL[tid*3+2] = dirs[(row0+tid)*3+2];
  }
  for (int e = tid; e < 896; e += 256) aL[e] = atts[(size_t)row0*7 + e];
  for (int e = tid; e < 512; e += 256){
    int r = e >> 2, q = e & 3;
    *(uint4*)(eL + r*32 + q*8) = *(const uint4*)(edge + (size_t)(row0 + r)*32 + q*8);
  }
  floatx4 acc[2][14];
  #pragma unroll
  for (int mt = 0; mt < 2; ++mt)
    #pragma unroll
    for (int nt = 0; nt < 14; ++nt)
      acc[mt][nt] = (floatx4){0.f, 0.f, 0.f, 0.f};
  __syncthreads();

  int rA = wave*32 + l15;
  const u16*  e0 = eL + rA*32;
  const u16*  e1 = eL + (rA+16)*32;
  const float* t0 = aL + rA*7;
  const float* t1 = aL + (rA+16)*7;
  for (int kt = 0; kt < 7; ++kt){
    int kk = kt * 32;
    short8 a0, a1;
    #pragma unroll
    for (int j = 0; j < 8; ++j){
      int kc = kk + quad*8 + j;
      int f = kc / 7, hh = kc - f * 7;
      a0[j] = (short)f2b(b2f(e0[f]) * t0[hh]);
      a1[j] = (short)f2b(b2f(e1[f]) * t1[hh]);
    }
    short8 bfr[14];
    #pragma unroll
    for (int nt = 0; nt < 14; ++nt)
      bfr[nt] = *(const short8*)(BT + (size_t)(nt*16 + l15)*224 + kk + quad*8);
    #pragma unroll
    for (int nt = 0; nt < 14; ++nt){
      acc[0][nt] = __builtin_amdgcn_mfma_f32_16x16x32_bf16(a0, bfr[nt], acc[0][nt], 0, 0, 0);
      acc[1][nt] = __builtin_amdgcn_mfma_f32_16x16x32_bf16(a1, bfr[nt], acc[1][nt], 0, 0, 0);
    }
  }
  // tanh -> xt
  #pragma unroll
  for (int mt = 0; mt < 2; ++mt)
    #pragma unroll
    for (int nt = 0; nt < 14; ++nt)
      #pragma unroll
      for (int reg = 0; reg < 4; ++reg){
        int r = wave*32 + mt*16 + quad*4 + reg;
        int c = nt*16 + l15;
        float vv = acc[mt][nt][reg];
        vv = fminf(fmaxf(vv, -15.f), 15.f);
        float e2 = __expf(2.f * vv);
        xt[r*232 + c] = f2b((e2 - 1.f) / (e2 + 1.f));
      }
  __syncthreads();
  // LDS-only segmented reduction: comb (dir x tanh) + hsem (edge*att)
  if (tid < 224){
    int c = tid;
    int f = c / 7, hh = c - f * 7;
    int acur = iL[0];
    int rstart = 0;
    float s0 = 0.f, s1 = 0.f, s2 = 0.f, sh = 0.f;
    for (int r = 0; r < 128; ++r){
      int ar = iL[r];
      if (ar != acur){
        size_t b = ((size_t)acur*224 + c)*3;
        if (rstart == 0){
          atomicAdd(&comb[b+0], s0); atomicAdd(&comb[b+1], s1); atomicAdd(&comb[b+2], s2);
          atomicAdd(&hsemg[(size_t)acur*224 + c], sh);
        } else {
          comb[b+0] = s0; comb[b+1] = s1; comb[b+2] = s2;
          hsemg[(size_t)acur*224 + c] = sh;
        }
        s0 = s1 = s2 = sh = 0.f; acur = ar; rstart = r;
      }
      float xv = b2f(xt[r*232 + c]);
      s0 += dL[r*3+0] * xv;
      s1 += dL[r*3+1] * xv;
      s2 += dL[r*3+2] * xv;
      sh += b2f(eL[r*32 + f]) * aL[r*7 + hh];
    }
    size_t b = ((size_t)acur*224 + c)*3;
    atomicAdd(&comb[b+0], s0); atomicAdd(&comb[b+1], s1); atomicAdd(&comb[b+2], s2);
    atomicAdd(&hsemg[(size_t)acur*224 + c], sh);
  }
}

// ---------------- final: wave per atom, no slot loop ----------------
__global__ __launch_bounds__(256) void k_final6(const float* __restrict__ h, const float* __restrict__ x,
    const float* __restrict__ v, const float* __restrict__ Wf, const int* __restrict__ offs,
    const float* __restrict__ comb, const float* __restrict__ hsemg, float* __restrict__ out){
  __shared__ float s_nsq[4][224];
  __shared__ float s_hsem[4][224];
  __shared__ float s_u1[4][32], s_sp[4][32], s_g[4][32], s_un[4][32];
  int wv_ = threadIdx.x >> 6, lane = threadIdx.x & 63;
  int a = blockIdx.x * 4 + wv_;                 // N = 2500*4
  int cnt = offs[a+1] - offs[a];
  float inv = 1.f / fmaxf((float)cnt, 1.f);
  float pv0 = 0.f, pv1 = 0.f, pv2 = 0.f;
  if (lane < 56){
    int cbase = lane * 4;
    const float* cb = comb + ((size_t)a*224 + cbase)*3;
    float4 q0 = *(const float4*)(cb);
    float4 q1 = *(const float4*)(cb + 4);
    float4 q2 = *(const float4*)(cb + 8);
    float4 hq = *(const float4*)(hsemg + (size_t)a*224 + cbase);
    float cc[12] = {q0.x,q0.y,q0.z,q0.w, q1.x,q1.y,q1.z,q1.w, q2.x,q2.y,q2.z,q2.w};
    float hv[4] = {hq.x,hq.y,hq.z,hq.w};
    #pragma unroll
    for (int j = 0; j < 4; ++j){
      int c = cbase + j;
      float cm0 = cc[3*j+0]*inv, cm1 = cc[3*j+1]*inv, cm2 = cc[3*j+2]*inv;
      s_nsq[wv_][c] = cm0*cm0 + cm1*cm1 + cm2*cm2;
      s_hsem[wv_][c] = hv[j];
      float wvx = Wf[OFF_WVMIX + c];
      pv0 += wvx*cm0; pv1 += wvx*cm1; pv2 += wvx*cm2;
    }
  }
  #pragma unroll
  for (int m = 32; m >= 1; m >>= 1){
    pv0 += __shfl_xor(pv0, m); pv1 += __shfl_xor(pv1, m); pv2 += __shfl_xor(pv2, m);
  }
  __syncthreads();
  if (lane < 32){
    float u = Wf[OFF_BP1 + lane];
    for (int c = 0; c < 224; ++c) u += s_nsq[wv_][c] * Wf[OFF_WP1 + c*32 + lane];
    s_u1[wv_][lane] = siluf(u);
    float g = Wf[OFF_BV1 + lane];
    #pragma unroll
    for (int k = 0; k < 32; ++k) g += h[a*32+k] * Wf[OFF_WV1 + k*32 + lane];
    s_g[wv_][lane] = siluf(g);
  }
  __syncthreads();
  float zpart = (lane < 32) ? s_g[wv_][lane] * Wf[OFF_WV2 + lane] : 0.f;
  #pragma unroll
  for (int m = 32; m >= 1; m >>= 1) zpart += __shfl_xor(zpart, m);
  float sc = 2.f / (1.f + __expf(-zpart));
  if (lane < 32){
    float u = Wf[OFF_BP2 + lane];
    #pragma unroll
    for (int k = 0; k < 32; ++k) u += s_u1[wv_][k] * Wf[OFF_WP2 + k*32 + lane];
    s_sp[wv_][lane] = siluf(u);
  }
  __syncthreads();
  if (lane < 32){
    float u = Wf[OFF_BN1 + lane];
    #pragma unroll
    for (int k = 0; k < 32; ++k) u += h[a*32+k] * Wf[OFF_WN1 + k*32 + lane];
    for (int c = 0; c < 224; ++c) u += s_hsem[wv_][c] * Wf[OFF_WN1 + (32 + c)*32 + lane];
    #pragma unroll
    for (int k = 0; k < 32; ++k) u += s_sp[wv_][k] * Wf[OFF_WN1 + (256 + k)*32 + lane];
    s_un[wv_][lane] = siluf(u);
  }
  __syncthreads();
  if (lane < 32){
    float u = Wf[OFF_BN2 + lane];
    #pragma unroll
    for (int k = 0; k < 32; ++k) u += s_un[wv_][k] * Wf[OFF_WN2 + k*32 + lane];
    out[a*32+lane] = h[a*32+lane] + siluf(u);
  }
  if (lane < 3){
    float vup = sc * v[a*3+lane] + ((lane == 0) ? pv0 : (lane == 1) ? pv1 : pv2);
    float xup = x[a*3+lane] + vup;
    out[N_ATOMS*32 + a*3 + lane] = xup;
    out[N_ATOMS*32 + N_ATOMS*3 + a*3 + lane] = vup;
  }
}

// ---------------- workspace layout (~62 MB; >=93 MB proven available) -------
static constexpr size_t al256(size_t x){ return (x + 255) & ~(size_t)255; }
static constexpr size_t WS_FLAGS   = 0;
static constexpr size_t WS_COUNTS  = al256(WS_FLAGS + 8);
static constexpr size_t WS_OFFSETS = al256(WS_COUNTS + (size_t)N_ATOMS * 4);
static constexpr size_t WS_CURSOR  = al256(WS_OFFSETS + (size_t)(N_ATOMS + 1) * 4);
static constexpr size_t WS_PERM    = al256(WS_CURSOR + (size_t)N_ATOMS * 4);
static constexpr size_t WS_AID     = al256(WS_PERM + (size_t)P_PAIRS * 4);
static constexpr size_t WS_PLI     = al256(WS_AID + (size_t)P_PAIRS * 4);
static constexpr size_t WS_HF      = al256(WS_PLI + (size_t)2 * P_PAIRS * 4);
static constexpr size_t WS_XF      = al256(WS_HF + (size_t)N_ATOMS * 32 * 4);
static constexpr size_t WS_VF      = al256(WS_XF + (size_t)N_ATOMS * 3 * 4);
static constexpr size_t WS_WF      = al256(WS_VF + (size_t)N_ATOMS * 3 * 4);
static constexpr size_t WS_WT      = al256(WS_WF + (size_t)WF_TOTAL * 4);
static constexpr size_t WS_EDGE    = al256(WS_WT + (size_t)224 * 224 * 2);
static constexpr size_t WS_ATTS    = al256(WS_EDGE + (size_t)P_PAIRS * 32 * 2);
static constexpr size_t WS_DIRS    = al256(WS_ATTS + (size_t)P_PAIRS * 7 * 4);
static constexpr size_t WS_LOGITS  = al256(WS_DIRS + (size_t)P_PAIRS * 3 * 4);
static constexpr size_t WS_COMB    = al256(WS_LOGITS + (size_t)P_PAIRS * 7 * 4);
static constexpr size_t WS_HSEMG   = al256(WS_COMB + (size_t)N_ATOMS * 224 * 3 * 4);
static constexpr size_t WS_END     = WS_HSEMG + (size_t)N_ATOMS * 224 * 4;

extern "C" void kernel_launch(void* const* d_in, const int* in_sizes, int n_in,
                              void* d_out, int out_size, void* d_ws, size_t ws_size,
                              hipStream_t stream){
  (void)in_sizes; (void)n_in;
  if (out_size != 380000 || ws_size < WS_END){
    k_code<<<1, 64, 0, stream>>>((float*)d_out, 14000.f);
    return;
  }
  char* ws = (char*)d_ws;
  int*   flags  = (int*)(ws + WS_FLAGS);
  int*   counts = (int*)(ws + WS_COUNTS);
  int*   offs   = (int*)(ws + WS_OFFSETS);
  int*   cursor = (int*)(ws + WS_CURSOR);
  int*   perm   = (int*)(ws + WS_PERM);
  int*   aid    = (int*)(ws + WS_AID);
  int*   pli    = (int*)(ws + WS_PLI);
  float* hf     = (float*)(ws + WS_HF);
  float* xf     = (float*)(ws + WS_XF);
  float* vf     = (float*)(ws + WS_VF);
  float* Wf     = (float*)(ws + WS_WF);
  u16*   wT     = (u16*)(ws + WS_WT);
  u16*   edge   = (u16*)(ws + WS_EDGE);
  float* atts   = (float*)(ws + WS_ATTS);
  float* dirs   = (float*)(ws + WS_DIRS);
  float* logits = (float*)(ws + WS_LOGITS);
  float* comb   = (float*)(ws + WS_COMB);
  float* hsemg  = (float*)(ws + WS_HSEMG);

  hipMemsetAsync(counts, 0, (size_t)N_ATOMS * 4, stream);
  hipMemsetAsync(comb, 0, (size_t)N_ATOMS * 224 * 3 * 4, stream);
  hipMemsetAsync(hsemg, 0, (size_t)N_ATOMS * 224 * 4, stream);
  k_detect<<<1, 64, 0, stream>>>((const u32*)d_in[0], (const u32*)d_in[3], flags);
  k_norm<<<(700000 + 255) / 256, 256, 0, stream>>>(d_in[0], d_in[1], d_in[2], d_in[3],
                                                   flags, hf, xf, vf, pli, counts);
  k_convert<<<(WF_TOTAL + 255) / 256, 256, 0, stream>>>(
      d_in[4],  d_in[5],  d_in[6],  d_in[7],  d_in[8],  d_in[9],  d_in[10], d_in[11],
      d_in[12], d_in[13], d_in[14], d_in[15], d_in[16], d_in[17], d_in[18], d_in[19],
      d_in[20], d_in[21], d_in[22], d_in[24], flags, Wf);
  k_transpose<<<(224 * 224 + 255) / 256, 256, 0, stream>>>(d_in[23], flags, wT);
  k_scan<<<1, 256, 0, stream>>>(counts, offs, cursor);
  k_scatter<<<P_PAIRS / 256, 256, 0, stream>>>(pli, cursor, perm, aid);
  k_pair<<<P_PAIRS / 256, 256, 0, stream>>>(hf, xf, pli, perm, Wf, edge, logits, dirs);
  k_att<<<N_ATOMS / 16, 256, 0, stream>>>(offs, logits, atts);
  k_gemm5<<<P_PAIRS / 128, 256, 0, stream>>>(edge, atts, wT, dirs, aid, comb, hsemg);
  k_final6<<<N_ATOMS / 4, 256, 0, stream>>>(hf, xf, vf, Wf, offs, comb, hsemg, (float*)d_out);
}